// Round 8
// baseline (278.025 us; speedup 1.0000x reference)
//
#include <hip/hip_runtime.h>

// TransformerClassification: 2-layer PyG TransformerConv GNN on MI355X.
// Round 8: proj1 occupancy fix (256-thread blocks, 64 nodes/block, 4 waves;
// was 1-wave blocks at 23% occupancy) + attn1 unroll-4 (8 gathers in flight).

#define N_NODES 50000
#define N_EDGES 800000
#define IN_F    128
#define HC      64      // heads*ch layer1
#define NH      4
#define CH      16
#define OUTF    7

#define NSB ((N_NODES + 255) / 256)   // 196 scan blocks

// ---------------- DPP helpers: butterfly reduce within each 16-lane row ----
__device__ __forceinline__ float dpp_add16(float x) {
    int t;
    t = __builtin_amdgcn_update_dpp(0, __float_as_int(x), 0xB1, 0xF, 0xF, false);
    x += __int_as_float(t);
    t = __builtin_amdgcn_update_dpp(0, __float_as_int(x), 0x4E, 0xF, 0xF, false);
    x += __int_as_float(t);
    t = __builtin_amdgcn_update_dpp(0, __float_as_int(x), 0x124, 0xF, 0xF, false);
    x += __int_as_float(t);
    t = __builtin_amdgcn_update_dpp(0, __float_as_int(x), 0x128, 0xF, 0xF, false);
    x += __int_as_float(t);
    return x;
}
__device__ __forceinline__ float dpp_max16(float x) {
    int t;
    t = __builtin_amdgcn_update_dpp(0, __float_as_int(x), 0xB1, 0xF, 0xF, false);
    x = fmaxf(x, __int_as_float(t));
    t = __builtin_amdgcn_update_dpp(0, __float_as_int(x), 0x4E, 0xF, 0xF, false);
    x = fmaxf(x, __int_as_float(t));
    t = __builtin_amdgcn_update_dpp(0, __float_as_int(x), 0x124, 0xF, 0xF, false);
    x = fmaxf(x, __int_as_float(t));
    t = __builtin_amdgcn_update_dpp(0, __float_as_int(x), 0x128, 0xF, 0xF, false);
    x = fmaxf(x, __int_as_float(t));
    return x;
}

// ---------------------------------------------------------------- init: zero the histogram
__global__ __launch_bounds__(256) void init_kernel(int* __restrict__ count)
{
    int i = blockIdx.x * 256 + threadIdx.x;
    if (i < N_NODES) count[i] = 0;
}

// ---------------------------------------------------------------- layer1 node projections
// 256 threads = 4 waves; 64 nodes/block; each wave owns 16 nodes.
// lane = output column; W rows loaded per wave (L1-shared across waves).
#define P1_NODES 64
__global__ __launch_bounds__(256) void proj1_kernel(
    const float* __restrict__ x,
    const float* __restrict__ Wq, const float* __restrict__ bq,
    const float* __restrict__ Wk, const float* __restrict__ bk,
    const float* __restrict__ Wv, const float* __restrict__ bv,
    const float* __restrict__ Ws, const float* __restrict__ bs,
    float* __restrict__ q1, float* __restrict__ k1,
    float* __restrict__ v1, float* __restrict__ s1)
{
    __shared__ float xs[P1_NODES][IN_F];   // 32 KB
    const int t    = threadIdx.x;
    const int lane = t & 63;               // output column
    const int wv   = t >> 6;               // wave 0..3
    const int n0   = blockIdx.x * P1_NODES;
    const int nval = (N_NODES - n0 < P1_NODES) ? (N_NODES - n0) : P1_NODES;

    const float4* xg  = (const float4*)(x + (size_t)n0 * IN_F);
    float4*       xsv = (float4*)&xs[0][0];
    const int nval4 = nval * (IN_F / 4);
    for (int j = t; j < nval4; j += 256)
        xsv[j] = xg[j];
    __syncthreads();

    float aq[16], ak[16], av[16], as_[16];
#pragma unroll
    for (int n = 0; n < 16; n++) { aq[n] = ak[n] = av[n] = as_[n] = 0.f; }

    const int nb = wv * 16;                // this wave's node base in tile
#pragma unroll 2
    for (int i = 0; i < IN_F; i++) {
        float wq = Wq[i * HC + lane];
        float wk = Wk[i * HC + lane];
        float wvv = Wv[i * HC + lane];
        float wss = Ws[i * HC + lane];
#pragma unroll
        for (int n = 0; n < 16; n++) {
            float xv = xs[nb + n][i];
            aq[n] += xv * wq;  ak[n] += xv * wk;
            av[n] += xv * wvv; as_[n] += xv * wss;
        }
    }
    float bqv = bq[lane], bkv = bk[lane], bvv = bv[lane], bsv = bs[lane];
#pragma unroll
    for (int n = 0; n < 16; n++) {
        int node = n0 + nb + n;
        if (node < N_NODES) {
            size_t o = (size_t)node * HC + lane;
            q1[o] = aq[n] + bqv; k1[o] = ak[n] + bkv;
            v1[o] = av[n] + bvv; s1[o] = as_[n] + bsv;
        }
    }
}

// ---------------------------------------------------------------- histogram of dst
__global__ __launch_bounds__(256) void hist_kernel(
    const int* __restrict__ ei, int* __restrict__ count)
{
    int e = blockIdx.x * 256 + threadIdx.x;
    if (e < N_EDGES) atomicAdd(count + ei[N_EDGES + e], 1);
}

// ---------------------------------------------------------------- scan phase 1
__global__ __launch_bounds__(256) void scan1_kernel(
    const int* __restrict__ count, int* __restrict__ pre, int* __restrict__ bsum)
{
    __shared__ int sdata[256];
    const int t = threadIdx.x;
    const int i = blockIdx.x * 256 + t;
    int v = (i < N_NODES) ? count[i] : 0;
    sdata[t] = v;
    __syncthreads();
    for (int d = 1; d < 256; d <<= 1) {
        int u = (t >= d) ? sdata[t - d] : 0;
        __syncthreads();
        sdata[t] += u;
        __syncthreads();
    }
    if (i < N_NODES) pre[i] = sdata[t] - v;
    if (t == 255) bsum[blockIdx.x] = sdata[255];
}

// ---------------------------------------------------------------- scan phase 2 (1 block)
__global__ __launch_bounds__(256) void scan2_kernel(
    int* __restrict__ bsum, int* __restrict__ bofs)
{
    __shared__ int sdata[256];
    const int t = threadIdx.x;
    int v = (t < NSB) ? bsum[t] : 0;
    sdata[t] = v;
    __syncthreads();
    for (int d = 1; d < 256; d <<= 1) {
        int u = (t >= d) ? sdata[t - d] : 0;
        __syncthreads();
        sdata[t] += u;
        __syncthreads();
    }
    if (t < NSB) bofs[t] = sdata[t] - v;
}

// ---------------------------------------------------------------- scan phase 3
__global__ __launch_bounds__(256) void scan3_kernel(
    const int* __restrict__ pre, const int* __restrict__ bofs,
    int* __restrict__ offs, int* __restrict__ cursor)
{
    const int i = blockIdx.x * 256 + threadIdx.x;
    if (i < N_NODES) {
        int o = pre[i] + bofs[i >> 8];
        offs[i] = o; cursor[i] = o;
    }
    if (i == 0) offs[N_NODES] = N_EDGES;
}

// ---------------------------------------------------------------- scatter: one packed 16B record per edge
__global__ __launch_bounds__(256) void scatter_kernel(
    const int* __restrict__ ei, const float* __restrict__ ea,
    int* __restrict__ cursor, float4* __restrict__ erec)
{
    int e = blockIdx.x * 256 + threadIdx.x;
    if (e >= N_EDGES) return;
    int dst = ei[N_EDGES + e];
    int pos = atomicAdd(cursor + dst, 1);
    float4 r;
    r.x = __int_as_float(ei[e]);
    r.y = ea[(size_t)e * 2];
    r.z = ea[(size_t)e * 2 + 1];
    r.w = 0.f;
    erec[pos] = r;
}

// ---------------------------------------------------------------- layer1 attention: one wave per dst node
// lane = channel; head = lane>>4. Online softmax, unroll-4 (8 gathers in
// flight), DPP head-sum. Fuses skip + ELU.
__global__ __launch_bounds__(256) void attn1_kernel(
    const int* __restrict__ offs, const float4* __restrict__ erec,
    const float* __restrict__ We,
    const float* __restrict__ q1, const float* __restrict__ k1,
    const float* __restrict__ v1, const float* __restrict__ s1,
    float* __restrict__ h)
{
    int n    = (blockIdx.x * 256 + threadIdx.x) >> 6;
    int lane = threadIdx.x & 63;
    if (n >= N_NODES) return;

    float qv  = q1[(size_t)n * HC + lane];
    float We0 = We[lane], We1 = We[HC + lane];
    int beg = offs[n], end = offs[n + 1];

    float m = -3.402823466e38f, l = 0.f, acc = 0.f;
    int i = beg;
    for (; i + 3 < end; i += 4) {
        float4 r0 = erec[i],     r1 = erec[i + 1];
        float4 r2 = erec[i + 2], r3 = erec[i + 3];
        size_t b0 = (size_t)__float_as_int(r0.x) * HC + lane;
        size_t b1 = (size_t)__float_as_int(r1.x) * HC + lane;
        size_t b2 = (size_t)__float_as_int(r2.x) * HC + lane;
        size_t b3 = (size_t)__float_as_int(r3.x) * HC + lane;
        float k0 = k1[b0], k1r = k1[b1], k2 = k1[b2], k3 = k1[b3];
        float v0 = v1[b0], v1r = v1[b1], v2 = v1[b2], v3 = v1[b3];
        float ec0 = r0.y * We0 + r0.z * We1;
        float ec1 = r1.y * We0 + r1.z * We1;
        float ec2 = r2.y * We0 + r2.z * We1;
        float ec3 = r3.y * We0 + r3.z * We1;
        float p0 = dpp_add16(qv * (k0 + ec0)) * 0.25f;
        float p1 = dpp_add16(qv * (k1r + ec1)) * 0.25f;
        float p2 = dpp_add16(qv * (k2 + ec2)) * 0.25f;
        float p3 = dpp_add16(qv * (k3 + ec3)) * 0.25f;
        float mx = fmaxf(fmaxf(p0, p1), fmaxf(p2, p3));
        float mn = fmaxf(m, mx);
        float sm = __expf(m - mn);
        float e0 = __expf(p0 - mn), e1 = __expf(p1 - mn);
        float e2 = __expf(p2 - mn), e3 = __expf(p3 - mn);
        l   = l   * sm + ((e0 + e1) + (e2 + e3));
        acc = acc * sm + (e0 * (v0 + ec0) + e1 * (v1r + ec1))
                       + (e2 * (v2 + ec2) + e3 * (v3 + ec3));
        m = mn;
    }
    for (; i < end; ++i) {
        float4 r0 = erec[i];
        size_t b0 = (size_t)__float_as_int(r0.x) * HC + lane;
        float ec0 = r0.y * We0 + r0.z * We1;
        float k0 = k1[b0] + ec0;
        float v0 = v1[b0] + ec0;
        float p0 = dpp_add16(qv * k0) * 0.25f;
        float mn = fmaxf(m, p0);
        float sm = __expf(m - mn);
        float e0 = __expf(p0 - mn);
        l   = l   * sm + e0;
        acc = acc * sm + e0 * v0;
        m = mn;
    }
    float att = (end > beg) ? acc / l : 0.f;
    float o = att + s1[(size_t)n * HC + lane];
    h[(size_t)n * HC + lane] = o > 0.f ? o : expm1f(o);   // ELU fused
}

// ---------------------------------------------------------------- layer2 node projections (64 -> 28), thread-per-node
__global__ __launch_bounds__(256) void proj2_kernel(
    const float* __restrict__ h,
    const float* __restrict__ Wq, const float* __restrict__ bq,
    const float* __restrict__ Wk, const float* __restrict__ bk,
    const float* __restrict__ Wv, const float* __restrict__ bv,
    const float* __restrict__ Ws, const float* __restrict__ bs,
    float* __restrict__ q2p, float* __restrict__ kv2, float* __restrict__ s2p)
{
    __shared__ float Wsm[HC][4][8];   // 8 KB
    __shared__ float Bsm[4][8];
    const int t = threadIdx.x;

    for (int j = t; j < HC * 28; j += 256) {
        int i = j / 28, r = j % 28, mtx = r / 7, c = r % 7;
        const float* W = (mtx == 0) ? Wq : (mtx == 1) ? Wk : (mtx == 2) ? Wv : Ws;
        Wsm[i][mtx][c] = W[i * OUTF + c];
    }
    for (int j = t; j < HC * 4; j += 256)          // zero the c=7 pad
        Wsm[j >> 2][j & 3][7] = 0.f;
    if (t < 32) {
        int mtx = t >> 3, c = t & 7;
        const float* B = (mtx == 0) ? bq : (mtx == 1) ? bk : (mtx == 2) ? bv : bs;
        Bsm[mtx][c] = (c < 7) ? B[c] : 0.f;
    }
    __syncthreads();

    int n = blockIdx.x * 256 + t;
    if (n >= N_NODES) return;

    float acc[4][8];
#pragma unroll
    for (int mtx = 0; mtx < 4; mtx++)
#pragma unroll
        for (int c = 0; c < 8; c++) acc[mtx][c] = Bsm[mtx][c];

    const float4* hp = (const float4*)(h + (size_t)n * HC);
#pragma unroll 4
    for (int i4 = 0; i4 < 16; i4++) {
        float4 hv = hp[i4];
        float hx[4] = { hv.x, hv.y, hv.z, hv.w };
#pragma unroll
        for (int e = 0; e < 4; e++) {
            int i = i4 * 4 + e;
#pragma unroll
            for (int mtx = 0; mtx < 4; mtx++) {
                float4 wa = *(const float4*)&Wsm[i][mtx][0];
                float4 wb = *(const float4*)&Wsm[i][mtx][4];
                acc[mtx][0] += hx[e] * wa.x; acc[mtx][1] += hx[e] * wa.y;
                acc[mtx][2] += hx[e] * wa.z; acc[mtx][3] += hx[e] * wa.w;
                acc[mtx][4] += hx[e] * wb.x; acc[mtx][5] += hx[e] * wb.y;
                acc[mtx][6] += hx[e] * wb.z; acc[mtx][7] += hx[e] * wb.w;
            }
        }
    }

    float4* q2v = (float4*)(q2p + (size_t)n * 8);
    q2v[0] = make_float4(acc[0][0], acc[0][1], acc[0][2], acc[0][3]);
    q2v[1] = make_float4(acc[0][4], acc[0][5], acc[0][6], acc[0][7]);
    float4* kvv = (float4*)(kv2 + (size_t)n * 16);
    kvv[0] = make_float4(acc[1][0], acc[1][1], acc[1][2], acc[1][3]);
    kvv[1] = make_float4(acc[1][4], acc[1][5], acc[1][6], acc[1][7]);
    kvv[2] = make_float4(acc[2][0], acc[2][1], acc[2][2], acc[2][3]);
    kvv[3] = make_float4(acc[2][4], acc[2][5], acc[2][6], acc[2][7]);
    float4* s2v = (float4*)(s2p + (size_t)n * 8);
    s2v[0] = make_float4(acc[3][0], acc[3][1], acc[3][2], acc[3][3]);
    s2v[1] = make_float4(acc[3][4], acc[3][5], acc[3][6], acc[3][7]);
}

// ---------------------------------------------------------------- layer2 attention: one wave per dst node
__global__ __launch_bounds__(256) void attn2_kernel(
    const int* __restrict__ offs, const float4* __restrict__ erec,
    const float* __restrict__ q2p, const float* __restrict__ kv2,
    const float* __restrict__ s2p, float* __restrict__ out)
{
    int n    = (blockIdx.x * 256 + threadIdx.x) >> 6;
    int lane = threadIdx.x & 63;
    if (n >= N_NODES) return;

    float4 qa = *(const float4*)(q2p + (size_t)n * 8);
    float4 qb = *(const float4*)(q2p + (size_t)n * 8 + 4);
    int beg = offs[n], end = offs[n + 1];

    float m = -3.402823466e38f, l = 0.f, a[OUTF];
#pragma unroll
    for (int c = 0; c < OUTF; c++) a[c] = 0.f;

    for (int i = beg + lane; i < end; i += 64) {
        int src = __float_as_int(erec[i].x);
        const float4* kvp = (const float4*)(kv2 + (size_t)src * 16);
        float4 ka = kvp[0], kb = kvp[1], va = kvp[2], vb = kvp[3];
        float dot = qa.x * ka.x + qa.y * ka.y + qa.z * ka.z + qa.w * ka.w
                  + qb.x * kb.x + qb.y * kb.y + qb.z * kb.z;
        float logit = dot * 0.37796447300922725f;       // 1/sqrt(7)
        float mn = fmaxf(m, logit);
        float sc = __expf(m - mn);
        float pe = __expf(logit - mn);
        l = l * sc + pe;
        a[0] = a[0] * sc + pe * va.x;
        a[1] = a[1] * sc + pe * va.y;
        a[2] = a[2] * sc + pe * va.z;
        a[3] = a[3] * sc + pe * va.w;
        a[4] = a[4] * sc + pe * vb.x;
        a[5] = a[5] * sc + pe * vb.y;
        a[6] = a[6] * sc + pe * vb.z;
        m = mn;
    }

    if (end > beg) {
        float M = dpp_max16(m);
        M = fmaxf(M, __shfl_xor(M, 16));
        M = fmaxf(M, __shfl_xor(M, 32));
        float sc = __expf(m - M);
        l *= sc;
#pragma unroll
        for (int c = 0; c < OUTF; c++) a[c] *= sc;
        l = dpp_add16(l); l += __shfl_xor(l, 16); l += __shfl_xor(l, 32);
#pragma unroll
        for (int c = 0; c < OUTF; c++) {
            float t = dpp_add16(a[c]);
            t += __shfl_xor(t, 16); t += __shfl_xor(t, 32);
            a[c] = t;
        }
        if (lane == 0) {
            float inv = 1.f / fmaxf(l, 1e-16f);
#pragma unroll
            for (int c = 0; c < OUTF; c++)
                out[(size_t)n * OUTF + c] = a[c] * inv + s2p[(size_t)n * 8 + c];
        }
    } else if (lane == 0) {
#pragma unroll
        for (int c = 0; c < OUTF; c++)
            out[(size_t)n * OUTF + c] = s2p[(size_t)n * 8 + c];
    }
}

// ----------------------------------------------------------------
extern "C" void kernel_launch(void* const* d_in, const int* in_sizes, int n_in,
                              void* d_out, int out_size, void* d_ws, size_t ws_size,
                              hipStream_t stream)
{
    const float* x    = (const float*)d_in[0];
    const float* ea   = (const float*)d_in[1];
    const int*   ei   = (const int*)d_in[2];
    const float* Wq1  = (const float*)d_in[3];
    const float* bq1  = (const float*)d_in[4];
    const float* Wk1  = (const float*)d_in[5];
    const float* bk1  = (const float*)d_in[6];
    const float* Wv1  = (const float*)d_in[7];
    const float* bv1  = (const float*)d_in[8];
    const float* We1  = (const float*)d_in[9];
    const float* Ws1  = (const float*)d_in[10];
    const float* bs1  = (const float*)d_in[11];
    const float* Wq2  = (const float*)d_in[12];
    const float* bq2  = (const float*)d_in[13];
    const float* Wk2  = (const float*)d_in[14];
    const float* bk2  = (const float*)d_in[15];
    const float* Wv2  = (const float*)d_in[16];
    const float* bv2  = (const float*)d_in[17];
    const float* Ws2  = (const float*)d_in[18];
    const float* bs2  = (const float*)d_in[19];
    float* out = (float*)d_out;

    // workspace layout (f32 words), ~84 MB total; all segments 16B-aligned.
    float* ws = (float*)d_ws;
    float*  q1   = ws;                               // N*64
    float*  k1   = q1 + (size_t)N_NODES * HC;
    float*  v1   = k1 + (size_t)N_NODES * HC;
    float*  s1   = v1 + (size_t)N_NODES * HC;
    float*  hbuf = q1;                               // alias: attn1 reads q1[slot] then writes h[slot]
    float4* erec = (float4*)(s1 + (size_t)N_NODES * HC);    // E x 16B
    float*  q2p  = (float*)(erec + N_EDGES);         // N*8
    float*  kv2  = q2p + (size_t)N_NODES * 8;        // N*16
    float*  s2p  = kv2 + (size_t)N_NODES * 16;       // N*8
    int*    count  = (int*)(s2p + (size_t)N_NODES * 8);     // N
    int*    offs   = count + N_NODES;                // N+1
    int*    cursor = offs + N_NODES + 1;             // N
    int*    pre    = cursor + N_NODES;               // N
    int*    bsum   = pre + N_NODES;                  // NSB
    int*    bofs   = bsum + NSB;                     // NSB

    const int eb = (N_EDGES + 255) / 256;
    const int nwave_blocks = (N_NODES * 64 + 255) / 256;

    init_kernel<<<(N_NODES + 255) / 256, 256, 0, stream>>>(count);

    proj1_kernel<<<(N_NODES + P1_NODES - 1) / P1_NODES, 256, 0, stream>>>(
        x, Wq1, bq1, Wk1, bk1, Wv1, bv1, Ws1, bs1, q1, k1, v1, s1);

    hist_kernel<<<eb, 256, 0, stream>>>(ei, count);
    scan1_kernel<<<NSB, 256, 0, stream>>>(count, pre, bsum);
    scan2_kernel<<<1, 256, 0, stream>>>(bsum, bofs);
    scan3_kernel<<<NSB, 256, 0, stream>>>(pre, bofs, offs, cursor);
    scatter_kernel<<<eb, 256, 0, stream>>>(ei, ea, cursor, erec);

    attn1_kernel<<<nwave_blocks, 256, 0, stream>>>(
        offs, erec, We1, q1, k1, v1, s1, hbuf);

    proj2_kernel<<<(N_NODES + 255) / 256, 256, 0, stream>>>(
        hbuf, Wq2, bq2, Wk2, bk2, Wv2, bv2, Ws2, bs2, q2p, kv2, s2p);

    attn2_kernel<<<nwave_blocks, 256, 0, stream>>>(
        offs, erec, q2p, kv2, s2p, out);
}

// Round 9
// 275.520 us; speedup vs baseline: 1.0091x; 1.0091x over previous
//
#include <hip/hip_runtime.h>

// TransformerClassification: 2-layer PyG TransformerConv GNN on MI355X.
// Round 9: proj1 rewritten as a proper LDS-tiled GEMM (64 nodes x 256 cols,
// K-chunks of 32, x and W both staged in LDS, no global loads in inner loop).
// Round-8's 4-wave variant kept global W loads in the chain and regressed.

#define N_NODES 50000
#define N_EDGES 800000
#define IN_F    128
#define HC      64      // heads*ch layer1
#define NH      4
#define CH      16
#define OUTF    7

#define NSB ((N_NODES + 255) / 256)   // 196 scan blocks

// ---------------- DPP helpers: butterfly reduce within each 16-lane row ----
__device__ __forceinline__ float dpp_add16(float x) {
    int t;
    t = __builtin_amdgcn_update_dpp(0, __float_as_int(x), 0xB1, 0xF, 0xF, false);
    x += __int_as_float(t);
    t = __builtin_amdgcn_update_dpp(0, __float_as_int(x), 0x4E, 0xF, 0xF, false);
    x += __int_as_float(t);
    t = __builtin_amdgcn_update_dpp(0, __float_as_int(x), 0x124, 0xF, 0xF, false);
    x += __int_as_float(t);
    t = __builtin_amdgcn_update_dpp(0, __float_as_int(x), 0x128, 0xF, 0xF, false);
    x += __int_as_float(t);
    return x;
}
__device__ __forceinline__ float dpp_max16(float x) {
    int t;
    t = __builtin_amdgcn_update_dpp(0, __float_as_int(x), 0xB1, 0xF, 0xF, false);
    x = fmaxf(x, __int_as_float(t));
    t = __builtin_amdgcn_update_dpp(0, __float_as_int(x), 0x4E, 0xF, 0xF, false);
    x = fmaxf(x, __int_as_float(t));
    t = __builtin_amdgcn_update_dpp(0, __float_as_int(x), 0x124, 0xF, 0xF, false);
    x = fmaxf(x, __int_as_float(t));
    t = __builtin_amdgcn_update_dpp(0, __float_as_int(x), 0x128, 0xF, 0xF, false);
    x = fmaxf(x, __int_as_float(t));
    return x;
}

// ---------------------------------------------------------------- init: zero the histogram
__global__ __launch_bounds__(256) void init_kernel(int* __restrict__ count)
{
    int i = blockIdx.x * 256 + threadIdx.x;
    if (i < N_NODES) count[i] = 0;
}

// ---------------------------------------------------------------- layer1 node projections
// LDS-tiled GEMM: 64 nodes x 256 cols per block, K-chunks of 32.
// Thread micro-tile: 4 nodes x 16 cols (one matrix). Inner loop is pure LDS+FMA.
#define P1_TN 64
__global__ __launch_bounds__(256) void proj1_kernel(
    const float* __restrict__ x,
    const float* __restrict__ Wq, const float* __restrict__ bq,
    const float* __restrict__ Wk, const float* __restrict__ bk,
    const float* __restrict__ Wv, const float* __restrict__ bv,
    const float* __restrict__ Ws, const float* __restrict__ bs,
    float* __restrict__ q1, float* __restrict__ k1,
    float* __restrict__ v1, float* __restrict__ s1)
{
    __shared__ float xs[P1_TN][33];    // 8.4 KB: x chunk, pad -> bank (n+i)%32
    __shared__ float Wsm[32][256];     // 32 KB: W chunk, 4 matrices side by side
    const int t  = threadIdx.x;
    const int n0 = blockIdx.x * P1_TN;
    const int nval = (N_NODES - n0 < P1_TN) ? (N_NODES - n0) : P1_TN;

    const int ng  = (t & 15) * 4;      // node group base (0..60)
    const int cg  = (t >> 4) * 16;     // col 0..255
    const int mtx = cg >> 6;           // which matrix
    const int c   = cg & 63;           // col within matrix

    const float* Wm = (mtx == 0) ? Wq : (mtx == 1) ? Wk : (mtx == 2) ? Wv : Ws;
    const float* Bm = (mtx == 0) ? bq : (mtx == 1) ? bk : (mtx == 2) ? bv : bs;
    float*       Om = (mtx == 0) ? q1 : (mtx == 1) ? k1 : (mtx == 2) ? v1 : s1;

    float acc[4][16];
    {
        float bias[16];
#pragma unroll
        for (int k4 = 0; k4 < 4; k4++) {
            float4 b = *(const float4*)(Bm + c + k4 * 4);
            bias[k4*4] = b.x; bias[k4*4+1] = b.y; bias[k4*4+2] = b.z; bias[k4*4+3] = b.w;
        }
#pragma unroll
        for (int j = 0; j < 4; j++)
#pragma unroll
            for (int k = 0; k < 16; k++) acc[j][k] = bias[k];
    }

    for (int k0 = 0; k0 < IN_F; k0 += 32) {
        __syncthreads();   // protect LDS reuse from previous chunk
        // stage x chunk: nval rows x 32 features
        for (int j = t; j < nval * 8; j += 256) {
            int n = j >> 3, i4 = (j & 7) * 4;
            float4 v = *(const float4*)(x + (size_t)(n0 + n) * IN_F + k0 + i4);
            xs[n][i4] = v.x; xs[n][i4+1] = v.y; xs[n][i4+2] = v.z; xs[n][i4+3] = v.w;
        }
        // stage W chunk: 32 rows x 256 cols (4 matrices)
        for (int f4 = t; f4 < 2048; f4 += 256) {
            int r = f4 >> 6, cc4 = (f4 & 63) * 4;
            int m = cc4 >> 6, cw = cc4 & 63;
            const float* Wp = (m == 0) ? Wq : (m == 1) ? Wk : (m == 2) ? Wv : Ws;
            *(float4*)&Wsm[r][cc4] = *(const float4*)(Wp + (size_t)(k0 + r) * HC + cw);
        }
        __syncthreads();

#pragma unroll 4
        for (int i = 0; i < 32; i++) {
            float x0 = xs[ng + 0][i];
            float x1 = xs[ng + 1][i];
            float x2 = xs[ng + 2][i];
            float x3 = xs[ng + 3][i];
            float4 wa = *(const float4*)&Wsm[i][cg];
            float4 wb = *(const float4*)&Wsm[i][cg + 4];
            float4 wc = *(const float4*)&Wsm[i][cg + 8];
            float4 wd = *(const float4*)&Wsm[i][cg + 12];
            float w[16] = { wa.x, wa.y, wa.z, wa.w, wb.x, wb.y, wb.z, wb.w,
                            wc.x, wc.y, wc.z, wc.w, wd.x, wd.y, wd.z, wd.w };
#pragma unroll
            for (int k = 0; k < 16; k++) {
                acc[0][k] += x0 * w[k];
                acc[1][k] += x1 * w[k];
                acc[2][k] += x2 * w[k];
                acc[3][k] += x3 * w[k];
            }
        }
    }

#pragma unroll
    for (int jj = 0; jj < 4; jj++) {
        int node = n0 + ng + jj;
        if (node < N_NODES) {
            float* op = Om + (size_t)node * HC + c;
#pragma unroll
            for (int k4 = 0; k4 < 4; k4++)
                *(float4*)(op + k4 * 4) = make_float4(acc[jj][k4*4], acc[jj][k4*4+1],
                                                      acc[jj][k4*4+2], acc[jj][k4*4+3]);
        }
    }
}

// ---------------------------------------------------------------- histogram of dst
__global__ __launch_bounds__(256) void hist_kernel(
    const int* __restrict__ ei, int* __restrict__ count)
{
    int e = blockIdx.x * 256 + threadIdx.x;
    if (e < N_EDGES) atomicAdd(count + ei[N_EDGES + e], 1);
}

// ---------------------------------------------------------------- scan phase 1
__global__ __launch_bounds__(256) void scan1_kernel(
    const int* __restrict__ count, int* __restrict__ pre, int* __restrict__ bsum)
{
    __shared__ int sdata[256];
    const int t = threadIdx.x;
    const int i = blockIdx.x * 256 + t;
    int v = (i < N_NODES) ? count[i] : 0;
    sdata[t] = v;
    __syncthreads();
    for (int d = 1; d < 256; d <<= 1) {
        int u = (t >= d) ? sdata[t - d] : 0;
        __syncthreads();
        sdata[t] += u;
        __syncthreads();
    }
    if (i < N_NODES) pre[i] = sdata[t] - v;
    if (t == 255) bsum[blockIdx.x] = sdata[255];
}

// ---------------------------------------------------------------- scan phase 2 (1 block)
__global__ __launch_bounds__(256) void scan2_kernel(
    int* __restrict__ bsum, int* __restrict__ bofs)
{
    __shared__ int sdata[256];
    const int t = threadIdx.x;
    int v = (t < NSB) ? bsum[t] : 0;
    sdata[t] = v;
    __syncthreads();
    for (int d = 1; d < 256; d <<= 1) {
        int u = (t >= d) ? sdata[t - d] : 0;
        __syncthreads();
        sdata[t] += u;
        __syncthreads();
    }
    if (t < NSB) bofs[t] = sdata[t] - v;
}

// ---------------------------------------------------------------- scan phase 3
__global__ __launch_bounds__(256) void scan3_kernel(
    const int* __restrict__ pre, const int* __restrict__ bofs,
    int* __restrict__ offs, int* __restrict__ cursor)
{
    const int i = blockIdx.x * 256 + threadIdx.x;
    if (i < N_NODES) {
        int o = pre[i] + bofs[i >> 8];
        offs[i] = o; cursor[i] = o;
    }
    if (i == 0) offs[N_NODES] = N_EDGES;
}

// ---------------------------------------------------------------- scatter: one packed 16B record per edge
__global__ __launch_bounds__(256) void scatter_kernel(
    const int* __restrict__ ei, const float* __restrict__ ea,
    int* __restrict__ cursor, float4* __restrict__ erec)
{
    int e = blockIdx.x * 256 + threadIdx.x;
    if (e >= N_EDGES) return;
    int dst = ei[N_EDGES + e];
    int pos = atomicAdd(cursor + dst, 1);
    float4 r;
    r.x = __int_as_float(ei[e]);
    r.y = ea[(size_t)e * 2];
    r.z = ea[(size_t)e * 2 + 1];
    r.w = 0.f;
    erec[pos] = r;
}

// ---------------------------------------------------------------- layer1 attention: one wave per dst node
__global__ __launch_bounds__(256) void attn1_kernel(
    const int* __restrict__ offs, const float4* __restrict__ erec,
    const float* __restrict__ We,
    const float* __restrict__ q1, const float* __restrict__ k1,
    const float* __restrict__ v1, const float* __restrict__ s1,
    float* __restrict__ h)
{
    int n    = (blockIdx.x * 256 + threadIdx.x) >> 6;
    int lane = threadIdx.x & 63;
    if (n >= N_NODES) return;

    float qv  = q1[(size_t)n * HC + lane];
    float We0 = We[lane], We1 = We[HC + lane];
    int beg = offs[n], end = offs[n + 1];

    float m = -3.402823466e38f, l = 0.f, acc = 0.f;
    int i = beg;
    for (; i + 3 < end; i += 4) {
        float4 r0 = erec[i],     r1 = erec[i + 1];
        float4 r2 = erec[i + 2], r3 = erec[i + 3];
        size_t b0 = (size_t)__float_as_int(r0.x) * HC + lane;
        size_t b1 = (size_t)__float_as_int(r1.x) * HC + lane;
        size_t b2 = (size_t)__float_as_int(r2.x) * HC + lane;
        size_t b3 = (size_t)__float_as_int(r3.x) * HC + lane;
        float k0 = k1[b0], k1r = k1[b1], k2 = k1[b2], k3 = k1[b3];
        float v0 = v1[b0], v1r = v1[b1], v2 = v1[b2], v3 = v1[b3];
        float ec0 = r0.y * We0 + r0.z * We1;
        float ec1 = r1.y * We0 + r1.z * We1;
        float ec2 = r2.y * We0 + r2.z * We1;
        float ec3 = r3.y * We0 + r3.z * We1;
        float p0 = dpp_add16(qv * (k0 + ec0)) * 0.25f;
        float p1 = dpp_add16(qv * (k1r + ec1)) * 0.25f;
        float p2 = dpp_add16(qv * (k2 + ec2)) * 0.25f;
        float p3 = dpp_add16(qv * (k3 + ec3)) * 0.25f;
        float mx = fmaxf(fmaxf(p0, p1), fmaxf(p2, p3));
        float mn = fmaxf(m, mx);
        float sm = __expf(m - mn);
        float e0 = __expf(p0 - mn), e1 = __expf(p1 - mn);
        float e2 = __expf(p2 - mn), e3 = __expf(p3 - mn);
        l   = l   * sm + ((e0 + e1) + (e2 + e3));
        acc = acc * sm + (e0 * (v0 + ec0) + e1 * (v1r + ec1))
                       + (e2 * (v2 + ec2) + e3 * (v3 + ec3));
        m = mn;
    }
    for (; i < end; ++i) {
        float4 r0 = erec[i];
        size_t b0 = (size_t)__float_as_int(r0.x) * HC + lane;
        float ec0 = r0.y * We0 + r0.z * We1;
        float k0 = k1[b0] + ec0;
        float v0 = v1[b0] + ec0;
        float p0 = dpp_add16(qv * k0) * 0.25f;
        float mn = fmaxf(m, p0);
        float sm = __expf(m - mn);
        float e0 = __expf(p0 - mn);
        l   = l   * sm + e0;
        acc = acc * sm + e0 * v0;
        m = mn;
    }
    float att = (end > beg) ? acc / l : 0.f;
    float o = att + s1[(size_t)n * HC + lane];
    h[(size_t)n * HC + lane] = o > 0.f ? o : expm1f(o);   // ELU fused
}

// ---------------------------------------------------------------- layer2 node projections (64 -> 28), thread-per-node
__global__ __launch_bounds__(256) void proj2_kernel(
    const float* __restrict__ h,
    const float* __restrict__ Wq, const float* __restrict__ bq,
    const float* __restrict__ Wk, const float* __restrict__ bk,
    const float* __restrict__ Wv, const float* __restrict__ bv,
    const float* __restrict__ Ws, const float* __restrict__ bs,
    float* __restrict__ q2p, float* __restrict__ kv2, float* __restrict__ s2p)
{
    __shared__ float Wsm[HC][4][8];   // 8 KB
    __shared__ float Bsm[4][8];
    const int t = threadIdx.x;

    for (int j = t; j < HC * 28; j += 256) {
        int i = j / 28, r = j % 28, mtx = r / 7, c = r % 7;
        const float* W = (mtx == 0) ? Wq : (mtx == 1) ? Wk : (mtx == 2) ? Wv : Ws;
        Wsm[i][mtx][c] = W[i * OUTF + c];
    }
    for (int j = t; j < HC * 4; j += 256)          // zero the c=7 pad
        Wsm[j >> 2][j & 3][7] = 0.f;
    if (t < 32) {
        int mtx = t >> 3, c = t & 7;
        const float* B = (mtx == 0) ? bq : (mtx == 1) ? bk : (mtx == 2) ? bv : bs;
        Bsm[mtx][c] = (c < 7) ? B[c] : 0.f;
    }
    __syncthreads();

    int n = blockIdx.x * 256 + t;
    if (n >= N_NODES) return;

    float acc[4][8];
#pragma unroll
    for (int mtx = 0; mtx < 4; mtx++)
#pragma unroll
        for (int c = 0; c < 8; c++) acc[mtx][c] = Bsm[mtx][c];

    const float4* hp = (const float4*)(h + (size_t)n * HC);
#pragma unroll 4
    for (int i4 = 0; i4 < 16; i4++) {
        float4 hv = hp[i4];
        float hx[4] = { hv.x, hv.y, hv.z, hv.w };
#pragma unroll
        for (int e = 0; e < 4; e++) {
            int i = i4 * 4 + e;
#pragma unroll
            for (int mtx = 0; mtx < 4; mtx++) {
                float4 wa = *(const float4*)&Wsm[i][mtx][0];
                float4 wb = *(const float4*)&Wsm[i][mtx][4];
                acc[mtx][0] += hx[e] * wa.x; acc[mtx][1] += hx[e] * wa.y;
                acc[mtx][2] += hx[e] * wa.z; acc[mtx][3] += hx[e] * wa.w;
                acc[mtx][4] += hx[e] * wb.x; acc[mtx][5] += hx[e] * wb.y;
                acc[mtx][6] += hx[e] * wb.z; acc[mtx][7] += hx[e] * wb.w;
            }
        }
    }

    float4* q2v = (float4*)(q2p + (size_t)n * 8);
    q2v[0] = make_float4(acc[0][0], acc[0][1], acc[0][2], acc[0][3]);
    q2v[1] = make_float4(acc[0][4], acc[0][5], acc[0][6], acc[0][7]);
    float4* kvv = (float4*)(kv2 + (size_t)n * 16);
    kvv[0] = make_float4(acc[1][0], acc[1][1], acc[1][2], acc[1][3]);
    kvv[1] = make_float4(acc[1][4], acc[1][5], acc[1][6], acc[1][7]);
    kvv[2] = make_float4(acc[2][0], acc[2][1], acc[2][2], acc[2][3]);
    kvv[3] = make_float4(acc[2][4], acc[2][5], acc[2][6], acc[2][7]);
    float4* s2v = (float4*)(s2p + (size_t)n * 8);
    s2v[0] = make_float4(acc[3][0], acc[3][1], acc[3][2], acc[3][3]);
    s2v[1] = make_float4(acc[3][4], acc[3][5], acc[3][6], acc[3][7]);
}

// ---------------------------------------------------------------- layer2 attention: one wave per dst node
__global__ __launch_bounds__(256) void attn2_kernel(
    const int* __restrict__ offs, const float4* __restrict__ erec,
    const float* __restrict__ q2p, const float* __restrict__ kv2,
    const float* __restrict__ s2p, float* __restrict__ out)
{
    int n    = (blockIdx.x * 256 + threadIdx.x) >> 6;
    int lane = threadIdx.x & 63;
    if (n >= N_NODES) return;

    float4 qa = *(const float4*)(q2p + (size_t)n * 8);
    float4 qb = *(const float4*)(q2p + (size_t)n * 8 + 4);
    int beg = offs[n], end = offs[n + 1];

    float m = -3.402823466e38f, l = 0.f, a[OUTF];
#pragma unroll
    for (int c = 0; c < OUTF; c++) a[c] = 0.f;

    for (int i = beg + lane; i < end; i += 64) {
        int src = __float_as_int(erec[i].x);
        const float4* kvp = (const float4*)(kv2 + (size_t)src * 16);
        float4 ka = kvp[0], kb = kvp[1], va = kvp[2], vb = kvp[3];
        float dot = qa.x * ka.x + qa.y * ka.y + qa.z * ka.z + qa.w * ka.w
                  + qb.x * kb.x + qb.y * kb.y + qb.z * kb.z;
        float logit = dot * 0.37796447300922725f;       // 1/sqrt(7)
        float mn = fmaxf(m, logit);
        float sc = __expf(m - mn);
        float pe = __expf(logit - mn);
        l = l * sc + pe;
        a[0] = a[0] * sc + pe * va.x;
        a[1] = a[1] * sc + pe * va.y;
        a[2] = a[2] * sc + pe * va.z;
        a[3] = a[3] * sc + pe * va.w;
        a[4] = a[4] * sc + pe * vb.x;
        a[5] = a[5] * sc + pe * vb.y;
        a[6] = a[6] * sc + pe * vb.z;
        m = mn;
    }

    if (end > beg) {
        float M = dpp_max16(m);
        M = fmaxf(M, __shfl_xor(M, 16));
        M = fmaxf(M, __shfl_xor(M, 32));
        float sc = __expf(m - M);
        l *= sc;
#pragma unroll
        for (int c = 0; c < OUTF; c++) a[c] *= sc;
        l = dpp_add16(l); l += __shfl_xor(l, 16); l += __shfl_xor(l, 32);
#pragma unroll
        for (int c = 0; c < OUTF; c++) {
            float t = dpp_add16(a[c]);
            t += __shfl_xor(t, 16); t += __shfl_xor(t, 32);
            a[c] = t;
        }
        if (lane == 0) {
            float inv = 1.f / fmaxf(l, 1e-16f);
#pragma unroll
            for (int c = 0; c < OUTF; c++)
                out[(size_t)n * OUTF + c] = a[c] * inv + s2p[(size_t)n * 8 + c];
        }
    } else if (lane == 0) {
#pragma unroll
        for (int c = 0; c < OUTF; c++)
            out[(size_t)n * OUTF + c] = s2p[(size_t)n * 8 + c];
    }
}

// ----------------------------------------------------------------
extern "C" void kernel_launch(void* const* d_in, const int* in_sizes, int n_in,
                              void* d_out, int out_size, void* d_ws, size_t ws_size,
                              hipStream_t stream)
{
    const float* x    = (const float*)d_in[0];
    const float* ea   = (const float*)d_in[1];
    const int*   ei   = (const int*)d_in[2];
    const float* Wq1  = (const float*)d_in[3];
    const float* bq1  = (const float*)d_in[4];
    const float* Wk1  = (const float*)d_in[5];
    const float* bk1  = (const float*)d_in[6];
    const float* Wv1  = (const float*)d_in[7];
    const float* bv1  = (const float*)d_in[8];
    const float* We1  = (const float*)d_in[9];
    const float* Ws1  = (const float*)d_in[10];
    const float* bs1  = (const float*)d_in[11];
    const float* Wq2  = (const float*)d_in[12];
    const float* bq2  = (const float*)d_in[13];
    const float* Wk2  = (const float*)d_in[14];
    const float* bk2  = (const float*)d_in[15];
    const float* Wv2  = (const float*)d_in[16];
    const float* bv2  = (const float*)d_in[17];
    const float* Ws2  = (const float*)d_in[18];
    const float* bs2  = (const float*)d_in[19];
    float* out = (float*)d_out;

    // workspace layout (f32 words), ~84 MB total; all segments 16B-aligned.
    float* ws = (float*)d_ws;
    float*  q1   = ws;                               // N*64
    float*  k1   = q1 + (size_t)N_NODES * HC;
    float*  v1   = k1 + (size_t)N_NODES * HC;
    float*  s1   = v1 + (size_t)N_NODES * HC;
    float*  hbuf = q1;                               // alias: attn1 reads q1[slot] then writes h[slot]
    float4* erec = (float4*)(s1 + (size_t)N_NODES * HC);    // E x 16B
    float*  q2p  = (float*)(erec + N_EDGES);         // N*8
    float*  kv2  = q2p + (size_t)N_NODES * 8;        // N*16
    float*  s2p  = kv2 + (size_t)N_NODES * 16;       // N*8
    int*    count  = (int*)(s2p + (size_t)N_NODES * 8);     // N
    int*    offs   = count + N_NODES;                // N+1
    int*    cursor = offs + N_NODES + 1;             // N
    int*    pre    = cursor + N_NODES;               // N
    int*    bsum   = pre + N_NODES;                  // NSB
    int*    bofs   = bsum + NSB;                     // NSB

    const int eb = (N_EDGES + 255) / 256;
    const int nwave_blocks = (N_NODES * 64 + 255) / 256;

    init_kernel<<<(N_NODES + 255) / 256, 256, 0, stream>>>(count);

    proj1_kernel<<<(N_NODES + P1_TN - 1) / P1_TN, 256, 0, stream>>>(
        x, Wq1, bq1, Wk1, bk1, Wv1, bv1, Ws1, bs1, q1, k1, v1, s1);

    hist_kernel<<<eb, 256, 0, stream>>>(ei, count);
    scan1_kernel<<<NSB, 256, 0, stream>>>(count, pre, bsum);
    scan2_kernel<<<1, 256, 0, stream>>>(bsum, bofs);
    scan3_kernel<<<NSB, 256, 0, stream>>>(pre, bofs, offs, cursor);
    scatter_kernel<<<eb, 256, 0, stream>>>(ei, ea, cursor, erec);

    attn1_kernel<<<nwave_blocks, 256, 0, stream>>>(
        offs, erec, We1, q1, k1, v1, s1, hbuf);

    proj2_kernel<<<(N_NODES + 255) / 256, 256, 0, stream>>>(
        hbuf, Wq2, bq2, Wk2, bk2, Wv2, bv2, Ws2, bs2, q2p, kv2, s2p);

    attn2_kernel<<<nwave_blocks, 256, 0, stream>>>(
        offs, erec, q2p, kv2, s2p, out);
}

// Round 10
// 264.122 us; speedup vs baseline: 1.0526x; 1.0432x over previous
//
#include <hip/hip_runtime.h>

// TransformerClassification: 2-layer PyG TransformerConv GNN on MI355X.
// Round 10: revert proj1 to round-7 best (72us, 0 conflicts; r8/r9 rewrites
// both regressed). attn1 redesigned: 4 edges per wave x 16 lanes per edge,
// float4 channels, DPP quad-reduce for head dots -> ~4x fewer VALU ops/edge.

#define N_NODES 50000
#define N_EDGES 800000
#define IN_F    128
#define HC      64      // heads*ch layer1
#define NH      4
#define CH      16
#define OUTF    7

#define NSB ((N_NODES + 255) / 256)   // 196 scan blocks

// ---------------- DPP helpers ----------------
// quad_perm(1,0,3,2)=0xB1 (xor1), quad_perm(2,3,0,1)=0x4E (xor2),
// row_ror:4=0x124, row_ror:8=0x128.
__device__ __forceinline__ float dpp_add16(float x) {
    int t;
    t = __builtin_amdgcn_update_dpp(0, __float_as_int(x), 0xB1, 0xF, 0xF, false);
    x += __int_as_float(t);
    t = __builtin_amdgcn_update_dpp(0, __float_as_int(x), 0x4E, 0xF, 0xF, false);
    x += __int_as_float(t);
    t = __builtin_amdgcn_update_dpp(0, __float_as_int(x), 0x124, 0xF, 0xF, false);
    x += __int_as_float(t);
    t = __builtin_amdgcn_update_dpp(0, __float_as_int(x), 0x128, 0xF, 0xF, false);
    x += __int_as_float(t);
    return x;
}
__device__ __forceinline__ float dpp_max16(float x) {
    int t;
    t = __builtin_amdgcn_update_dpp(0, __float_as_int(x), 0xB1, 0xF, 0xF, false);
    x = fmaxf(x, __int_as_float(t));
    t = __builtin_amdgcn_update_dpp(0, __float_as_int(x), 0x4E, 0xF, 0xF, false);
    x = fmaxf(x, __int_as_float(t));
    t = __builtin_amdgcn_update_dpp(0, __float_as_int(x), 0x124, 0xF, 0xF, false);
    x = fmaxf(x, __int_as_float(t));
    t = __builtin_amdgcn_update_dpp(0, __float_as_int(x), 0x128, 0xF, 0xF, false);
    x = fmaxf(x, __int_as_float(t));
    return x;
}
// sum across the 4 lanes of a HW quad (all 4 lanes get the total)
__device__ __forceinline__ float dpp_add4(float x) {
    int t;
    t = __builtin_amdgcn_update_dpp(0, __float_as_int(x), 0xB1, 0xF, 0xF, false);
    x += __int_as_float(t);
    t = __builtin_amdgcn_update_dpp(0, __float_as_int(x), 0x4E, 0xF, 0xF, false);
    x += __int_as_float(t);
    return x;
}

// ---------------------------------------------------------------- init: zero the histogram
__global__ __launch_bounds__(256) void init_kernel(int* __restrict__ count)
{
    int i = blockIdx.x * 256 + threadIdx.x;
    if (i < N_NODES) count[i] = 0;
}

// ---------------------------------------------------------------- layer1 node projections
// Round-7 best: 16 nodes per block, 64 threads (one per output column).
#define P1_NB 16
__global__ __launch_bounds__(64) void proj1_kernel(
    const float* __restrict__ x,
    const float* __restrict__ Wq, const float* __restrict__ bq,
    const float* __restrict__ Wk, const float* __restrict__ bk,
    const float* __restrict__ Wv, const float* __restrict__ bv,
    const float* __restrict__ Ws, const float* __restrict__ bs,
    float* __restrict__ q1, float* __restrict__ k1,
    float* __restrict__ v1, float* __restrict__ s1)
{
    __shared__ float xs[P1_NB][IN_F];
    const int t  = threadIdx.x;          // 0..63 = output column
    const int n0 = blockIdx.x * P1_NB;

    for (int j = t; j < P1_NB * IN_F; j += 64)
        xs[j >> 7][j & 127] = x[(size_t)n0 * IN_F + j];
    __syncthreads();

    float aq[P1_NB], ak[P1_NB], av[P1_NB], as_[P1_NB];
#pragma unroll
    for (int n = 0; n < P1_NB; n++) { aq[n] = ak[n] = av[n] = as_[n] = 0.f; }

    for (int i = 0; i < IN_F; i++) {
        float wq = Wq[i * HC + t];
        float wk = Wk[i * HC + t];
        float wv = Wv[i * HC + t];
        float ws = Ws[i * HC + t];
#pragma unroll
        for (int n = 0; n < P1_NB; n++) {
            float xv = xs[n][i];
            aq[n] += xv * wq; ak[n] += xv * wk;
            av[n] += xv * wv; as_[n] += xv * ws;
        }
    }
    float bqv = bq[t], bkv = bk[t], bvv = bv[t], bsv = bs[t];
#pragma unroll
    for (int n = 0; n < P1_NB; n++) {
        size_t o = (size_t)(n0 + n) * HC + t;
        q1[o] = aq[n] + bqv; k1[o] = ak[n] + bkv;
        v1[o] = av[n] + bvv; s1[o] = as_[n] + bsv;
    }
}

// ---------------------------------------------------------------- histogram of dst
__global__ __launch_bounds__(256) void hist_kernel(
    const int* __restrict__ ei, int* __restrict__ count)
{
    int e = blockIdx.x * 256 + threadIdx.x;
    if (e < N_EDGES) atomicAdd(count + ei[N_EDGES + e], 1);
}

// ---------------------------------------------------------------- scan phase 1
__global__ __launch_bounds__(256) void scan1_kernel(
    const int* __restrict__ count, int* __restrict__ pre, int* __restrict__ bsum)
{
    __shared__ int sdata[256];
    const int t = threadIdx.x;
    const int i = blockIdx.x * 256 + t;
    int v = (i < N_NODES) ? count[i] : 0;
    sdata[t] = v;
    __syncthreads();
    for (int d = 1; d < 256; d <<= 1) {
        int u = (t >= d) ? sdata[t - d] : 0;
        __syncthreads();
        sdata[t] += u;
        __syncthreads();
    }
    if (i < N_NODES) pre[i] = sdata[t] - v;
    if (t == 255) bsum[blockIdx.x] = sdata[255];
}

// ---------------------------------------------------------------- scan phase 2 (1 block)
__global__ __launch_bounds__(256) void scan2_kernel(
    int* __restrict__ bsum, int* __restrict__ bofs)
{
    __shared__ int sdata[256];
    const int t = threadIdx.x;
    int v = (t < NSB) ? bsum[t] : 0;
    sdata[t] = v;
    __syncthreads();
    for (int d = 1; d < 256; d <<= 1) {
        int u = (t >= d) ? sdata[t - d] : 0;
        __syncthreads();
        sdata[t] += u;
        __syncthreads();
    }
    if (t < NSB) bofs[t] = sdata[t] - v;
}

// ---------------------------------------------------------------- scan phase 3
__global__ __launch_bounds__(256) void scan3_kernel(
    const int* __restrict__ pre, const int* __restrict__ bofs,
    int* __restrict__ offs, int* __restrict__ cursor)
{
    const int i = blockIdx.x * 256 + threadIdx.x;
    if (i < N_NODES) {
        int o = pre[i] + bofs[i >> 8];
        offs[i] = o; cursor[i] = o;
    }
    if (i == 0) offs[N_NODES] = N_EDGES;
}

// ---------------------------------------------------------------- scatter: one packed 16B record per edge
__global__ __launch_bounds__(256) void scatter_kernel(
    const int* __restrict__ ei, const float* __restrict__ ea,
    int* __restrict__ cursor, float4* __restrict__ erec)
{
    int e = blockIdx.x * 256 + threadIdx.x;
    if (e >= N_EDGES) return;
    int dst = ei[N_EDGES + e];
    int pos = atomicAdd(cursor + dst, 1);
    float4 r;
    r.x = __int_as_float(ei[e]);
    r.y = ea[(size_t)e * 2];
    r.z = ea[(size_t)e * 2 + 1];
    r.w = 0.f;
    erec[pos] = r;
}

// ---------------------------------------------------------------- layer1 attention: one wave per dst node
// 4 edges per wave (g = lane>>4), 16 lanes per edge (s = lane&15 owns
// channels 4s..4s+3 as float4). Head h = s>>2 -> dot reduce = DPP quad sum.
// Online softmax per group; cross-group merge at end. Fuses skip + ELU.
__global__ __launch_bounds__(256) void attn1_kernel(
    const int* __restrict__ offs, const float4* __restrict__ erec,
    const float* __restrict__ We,
    const float* __restrict__ q1, const float* __restrict__ k1,
    const float* __restrict__ v1, const float* __restrict__ s1,
    float* __restrict__ h)
{
    int n    = (blockIdx.x * 256 + threadIdx.x) >> 6;
    int lane = threadIdx.x & 63;
    if (n >= N_NODES) return;
    const int g = lane >> 4;     // edge slot 0..3
    const int s = lane & 15;     // channel quad: channels 4s..4s+3

    const float4 qv  = *(const float4*)(q1 + (size_t)n * HC + s * 4);
    const float4 We0 = *(const float4*)(We + s * 4);
    const float4 We1 = *(const float4*)(We + HC + s * 4);
    const int beg = offs[n], end = offs[n + 1];

    float m = -3.402823466e38f, l = 0.f;
    float4 acc = make_float4(0.f, 0.f, 0.f, 0.f);

    for (int base = beg; base < end; base += 4) {
        int i = base + g;
        bool valid = (i < end);
        float4 r = erec[valid ? i : beg];
        int src = __float_as_int(r.x);
        size_t b = (size_t)src * HC + s * 4;
        float4 kk = *(const float4*)(k1 + b);
        float4 vv = *(const float4*)(v1 + b);
        float4 ec = make_float4(r.y * We0.x + r.z * We1.x,
                                r.y * We0.y + r.z * We1.y,
                                r.y * We0.z + r.z * We1.z,
                                r.y * We0.w + r.z * We1.w);
        float d = qv.x * (kk.x + ec.x) + qv.y * (kk.y + ec.y)
                + qv.z * (kk.z + ec.z) + qv.w * (kk.w + ec.w);
        d = dpp_add4(d);                          // head dot (16 channels)
        float logit = valid ? d * 0.25f : -3.402823466e38f;   // 1/sqrt(16)
        float mn = fmaxf(m, logit);
        float sm = __expf(m - mn);
        float pe = valid ? __expf(logit - mn) : 0.f;
        l = l * sm + pe;
        acc.x = acc.x * sm + pe * (vv.x + ec.x);
        acc.y = acc.y * sm + pe * (vv.y + ec.y);
        acc.z = acc.z * sm + pe * (vv.z + ec.z);
        acc.w = acc.w * sm + pe * (vv.w + ec.w);
        m = mn;
    }

    if (end > beg) {
        // merge 4 edge-groups: max, rescale, sum (lanes with equal s align)
        float M = fmaxf(m, __shfl_xor(m, 16));
        M = fmaxf(M, __shfl_xor(M, 32));
        float sc = __expf(m - M);                 // empty group: -inf -> 0
        l *= sc; acc.x *= sc; acc.y *= sc; acc.z *= sc; acc.w *= sc;
        l += __shfl_xor(l, 16);  l += __shfl_xor(l, 32);
        acc.x += __shfl_xor(acc.x, 16); acc.x += __shfl_xor(acc.x, 32);
        acc.y += __shfl_xor(acc.y, 16); acc.y += __shfl_xor(acc.y, 32);
        acc.z += __shfl_xor(acc.z, 16); acc.z += __shfl_xor(acc.z, 32);
        acc.w += __shfl_xor(acc.w, 16); acc.w += __shfl_xor(acc.w, 32);
        if (lane < 16) {
            float inv = 1.f / l;
            float4 sk = *(const float4*)(s1 + (size_t)n * HC + s * 4);
            float4 o;
            o.x = acc.x * inv + sk.x;
            o.y = acc.y * inv + sk.y;
            o.z = acc.z * inv + sk.z;
            o.w = acc.w * inv + sk.w;
            o.x = o.x > 0.f ? o.x : expm1f(o.x);
            o.y = o.y > 0.f ? o.y : expm1f(o.y);
            o.z = o.z > 0.f ? o.z : expm1f(o.z);
            o.w = o.w > 0.f ? o.w : expm1f(o.w);
            *(float4*)(h + (size_t)n * HC + s * 4) = o;
        }
    } else if (lane < 16) {
        float4 sk = *(const float4*)(s1 + (size_t)n * HC + s * 4);
        float4 o;
        o.x = sk.x > 0.f ? sk.x : expm1f(sk.x);
        o.y = sk.y > 0.f ? sk.y : expm1f(sk.y);
        o.z = sk.z > 0.f ? sk.z : expm1f(sk.z);
        o.w = sk.w > 0.f ? sk.w : expm1f(sk.w);
        *(float4*)(h + (size_t)n * HC + s * 4) = o;
    }
}

// ---------------------------------------------------------------- layer2 node projections (64 -> 28), thread-per-node
__global__ __launch_bounds__(256) void proj2_kernel(
    const float* __restrict__ h,
    const float* __restrict__ Wq, const float* __restrict__ bq,
    const float* __restrict__ Wk, const float* __restrict__ bk,
    const float* __restrict__ Wv, const float* __restrict__ bv,
    const float* __restrict__ Ws, const float* __restrict__ bs,
    float* __restrict__ q2p, float* __restrict__ kv2, float* __restrict__ s2p)
{
    __shared__ float Wsm[HC][4][8];   // 8 KB
    __shared__ float Bsm[4][8];
    const int t = threadIdx.x;

    for (int j = t; j < HC * 28; j += 256) {
        int i = j / 28, r = j % 28, mtx = r / 7, c = r % 7;
        const float* W = (mtx == 0) ? Wq : (mtx == 1) ? Wk : (mtx == 2) ? Wv : Ws;
        Wsm[i][mtx][c] = W[i * OUTF + c];
    }
    for (int j = t; j < HC * 4; j += 256)          // zero the c=7 pad
        Wsm[j >> 2][j & 3][7] = 0.f;
    if (t < 32) {
        int mtx = t >> 3, c = t & 7;
        const float* B = (mtx == 0) ? bq : (mtx == 1) ? bk : (mtx == 2) ? bv : bs;
        Bsm[mtx][c] = (c < 7) ? B[c] : 0.f;
    }
    __syncthreads();

    int n = blockIdx.x * 256 + t;
    if (n >= N_NODES) return;

    float acc[4][8];
#pragma unroll
    for (int mtx = 0; mtx < 4; mtx++)
#pragma unroll
        for (int c = 0; c < 8; c++) acc[mtx][c] = Bsm[mtx][c];

    const float4* hp = (const float4*)(h + (size_t)n * HC);
#pragma unroll 4
    for (int i4 = 0; i4 < 16; i4++) {
        float4 hv = hp[i4];
        float hx[4] = { hv.x, hv.y, hv.z, hv.w };
#pragma unroll
        for (int e = 0; e < 4; e++) {
            int i = i4 * 4 + e;
#pragma unroll
            for (int mtx = 0; mtx < 4; mtx++) {
                float4 wa = *(const float4*)&Wsm[i][mtx][0];
                float4 wb = *(const float4*)&Wsm[i][mtx][4];
                acc[mtx][0] += hx[e] * wa.x; acc[mtx][1] += hx[e] * wa.y;
                acc[mtx][2] += hx[e] * wa.z; acc[mtx][3] += hx[e] * wa.w;
                acc[mtx][4] += hx[e] * wb.x; acc[mtx][5] += hx[e] * wb.y;
                acc[mtx][6] += hx[e] * wb.z; acc[mtx][7] += hx[e] * wb.w;
            }
        }
    }

    float4* q2v = (float4*)(q2p + (size_t)n * 8);
    q2v[0] = make_float4(acc[0][0], acc[0][1], acc[0][2], acc[0][3]);
    q2v[1] = make_float4(acc[0][4], acc[0][5], acc[0][6], acc[0][7]);
    float4* kvv = (float4*)(kv2 + (size_t)n * 16);
    kvv[0] = make_float4(acc[1][0], acc[1][1], acc[1][2], acc[1][3]);
    kvv[1] = make_float4(acc[1][4], acc[1][5], acc[1][6], acc[1][7]);
    kvv[2] = make_float4(acc[2][0], acc[2][1], acc[2][2], acc[2][3]);
    kvv[3] = make_float4(acc[2][4], acc[2][5], acc[2][6], acc[2][7]);
    float4* s2v = (float4*)(s2p + (size_t)n * 8);
    s2v[0] = make_float4(acc[3][0], acc[3][1], acc[3][2], acc[3][3]);
    s2v[1] = make_float4(acc[3][4], acc[3][5], acc[3][6], acc[3][7]);
}

// ---------------------------------------------------------------- layer2 attention: one wave per dst node
__global__ __launch_bounds__(256) void attn2_kernel(
    const int* __restrict__ offs, const float4* __restrict__ erec,
    const float* __restrict__ q2p, const float* __restrict__ kv2,
    const float* __restrict__ s2p, float* __restrict__ out)
{
    int n    = (blockIdx.x * 256 + threadIdx.x) >> 6;
    int lane = threadIdx.x & 63;
    if (n >= N_NODES) return;

    float4 qa = *(const float4*)(q2p + (size_t)n * 8);
    float4 qb = *(const float4*)(q2p + (size_t)n * 8 + 4);
    int beg = offs[n], end = offs[n + 1];

    float m = -3.402823466e38f, l = 0.f, a[OUTF];
#pragma unroll
    for (int c = 0; c < OUTF; c++) a[c] = 0.f;

    for (int i = beg + lane; i < end; i += 64) {
        int src = __float_as_int(erec[i].x);
        const float4* kvp = (const float4*)(kv2 + (size_t)src * 16);
        float4 ka = kvp[0], kb = kvp[1], va = kvp[2], vb = kvp[3];
        float dot = qa.x * ka.x + qa.y * ka.y + qa.z * ka.z + qa.w * ka.w
                  + qb.x * kb.x + qb.y * kb.y + qb.z * kb.z;
        float logit = dot * 0.37796447300922725f;       // 1/sqrt(7)
        float mn = fmaxf(m, logit);
        float sc = __expf(m - mn);
        float pe = __expf(logit - mn);
        l = l * sc + pe;
        a[0] = a[0] * sc + pe * va.x;
        a[1] = a[1] * sc + pe * va.y;
        a[2] = a[2] * sc + pe * va.z;
        a[3] = a[3] * sc + pe * va.w;
        a[4] = a[4] * sc + pe * vb.x;
        a[5] = a[5] * sc + pe * vb.y;
        a[6] = a[6] * sc + pe * vb.z;
        m = mn;
    }

    if (end > beg) {
        float M = dpp_max16(m);
        M = fmaxf(M, __shfl_xor(M, 16));
        M = fmaxf(M, __shfl_xor(M, 32));
        float sc = __expf(m - M);
        l *= sc;
#pragma unroll
        for (int c = 0; c < OUTF; c++) a[c] *= sc;
        l = dpp_add16(l); l += __shfl_xor(l, 16); l += __shfl_xor(l, 32);
#pragma unroll
        for (int c = 0; c < OUTF; c++) {
            float t = dpp_add16(a[c]);
            t += __shfl_xor(t, 16); t += __shfl_xor(t, 32);
            a[c] = t;
        }
        if (lane == 0) {
            float inv = 1.f / fmaxf(l, 1e-16f);
#pragma unroll
            for (int c = 0; c < OUTF; c++)
                out[(size_t)n * OUTF + c] = a[c] * inv + s2p[(size_t)n * 8 + c];
        }
    } else if (lane == 0) {
#pragma unroll
        for (int c = 0; c < OUTF; c++)
            out[(size_t)n * OUTF + c] = s2p[(size_t)n * 8 + c];
    }
}

// ----------------------------------------------------------------
extern "C" void kernel_launch(void* const* d_in, const int* in_sizes, int n_in,
                              void* d_out, int out_size, void* d_ws, size_t ws_size,
                              hipStream_t stream)
{
    const float* x    = (const float*)d_in[0];
    const float* ea   = (const float*)d_in[1];
    const int*   ei   = (const int*)d_in[2];
    const float* Wq1  = (const float*)d_in[3];
    const float* bq1  = (const float*)d_in[4];
    const float* Wk1  = (const float*)d_in[5];
    const float* bk1  = (const float*)d_in[6];
    const float* Wv1  = (const float*)d_in[7];
    const float* bv1  = (const float*)d_in[8];
    const float* We1  = (const float*)d_in[9];
    const float* Ws1  = (const float*)d_in[10];
    const float* bs1  = (const float*)d_in[11];
    const float* Wq2  = (const float*)d_in[12];
    const float* bq2  = (const float*)d_in[13];
    const float* Wk2  = (const float*)d_in[14];
    const float* bk2  = (const float*)d_in[15];
    const float* Wv2  = (const float*)d_in[16];
    const float* bv2  = (const float*)d_in[17];
    const float* Ws2  = (const float*)d_in[18];
    const float* bs2  = (const float*)d_in[19];
    float* out = (float*)d_out;

    // workspace layout (f32 words), ~84 MB total; all segments 16B-aligned.
    float* ws = (float*)d_ws;
    float*  q1   = ws;                               // N*64
    float*  k1   = q1 + (size_t)N_NODES * HC;
    float*  v1   = k1 + (size_t)N_NODES * HC;
    float*  s1   = v1 + (size_t)N_NODES * HC;
    float*  hbuf = q1;                               // alias: attn1 reads q1 row n then writes h row n
    float4* erec = (float4*)(s1 + (size_t)N_NODES * HC);    // E x 16B
    float*  q2p  = (float*)(erec + N_EDGES);         // N*8
    float*  kv2  = q2p + (size_t)N_NODES * 8;        // N*16
    float*  s2p  = kv2 + (size_t)N_NODES * 16;       // N*8
    int*    count  = (int*)(s2p + (size_t)N_NODES * 8);     // N
    int*    offs   = count + N_NODES;                // N+1
    int*    cursor = offs + N_NODES + 1;             // N
    int*    pre    = cursor + N_NODES;               // N
    int*    bsum   = pre + N_NODES;                  // NSB
    int*    bofs   = bsum + NSB;                     // NSB

    const int eb = (N_EDGES + 255) / 256;
    const int nwave_blocks = (N_NODES * 64 + 255) / 256;

    init_kernel<<<(N_NODES + 255) / 256, 256, 0, stream>>>(count);

    proj1_kernel<<<N_NODES / P1_NB, 64, 0, stream>>>(
        x, Wq1, bq1, Wk1, bk1, Wv1, bv1, Ws1, bs1, q1, k1, v1, s1);

    hist_kernel<<<eb, 256, 0, stream>>>(ei, count);
    scan1_kernel<<<NSB, 256, 0, stream>>>(count, pre, bsum);
    scan2_kernel<<<1, 256, 0, stream>>>(bsum, bofs);
    scan3_kernel<<<NSB, 256, 0, stream>>>(pre, bofs, offs, cursor);
    scatter_kernel<<<eb, 256, 0, stream>>>(ei, ea, cursor, erec);

    attn1_kernel<<<nwave_blocks, 256, 0, stream>>>(
        offs, erec, We1, q1, k1, v1, s1, hbuf);

    proj2_kernel<<<(N_NODES + 255) / 256, 256, 0, stream>>>(
        hbuf, Wq2, bq2, Wk2, bk2, Wv2, bv2, Ws2, bs2, q2p, kv2, s2p);

    attn2_kernel<<<nwave_blocks, 256, 0, stream>>>(
        offs, erec, q2p, kv2, s2p, out);
}